// Round 1
// baseline (955.122 us; speedup 1.0000x reference)
//
#include <hip/hip_runtime.h>
#include <hip/hip_bf16.h>

// out[b,o] = sum_n relu( (s[b]-v[n]) . W[n,o,:] + bias[n,o] )
//          = sum_n relu( s[b].W[n,o,:] + c[n,o] ),  c[n,o] = bias[n,o] - v[n].W[n,o,:]
//
// Kernel 1: c into d_ws (fp32, memory-bound, reads W once).
// Kernel 2: fused bf16-MFMA GEMM. A = s staged once per block in swizzled LDS;
//           W fragments global->reg direct (waves own disjoint o-columns).

typedef __attribute__((ext_vector_type(8))) short  bf16x8;
typedef __attribute__((ext_vector_type(4))) float  f32x4;

constexpr int B   = 1024;
constexpr int N   = 64;
constexpr int D   = 512;
constexpr int OUT = 2048;

constexpr int BM = 128;   // rows (b) per block
constexpr int BO = 64;    // cols (o) per block; 4 waves x 16 cols

static __device__ __forceinline__ unsigned short f2bf(float f) {
    // round-to-nearest-even bf16
    unsigned int u = __builtin_bit_cast(unsigned int, f);
    u += 0x7FFFu + ((u >> 16) & 1u);
    return (unsigned short)(u >> 16);
}

static __device__ __forceinline__ bf16x8 cvt8(float4 a, float4 b) {
    bf16x8 r;
    r[0] = (short)f2bf(a.x); r[1] = (short)f2bf(a.y);
    r[2] = (short)f2bf(a.z); r[3] = (short)f2bf(a.w);
    r[4] = (short)f2bf(b.x); r[5] = (short)f2bf(b.y);
    r[6] = (short)f2bf(b.z); r[7] = (short)f2bf(b.w);
    return r;
}

// ---------------- Kernel 1: c[n,o] = bias[n,o] - dot(v[n], W[n,o,:]) ----------------
__global__ __launch_bounds__(256) void c_kernel(const float* __restrict__ V,
                                                const float* __restrict__ W,
                                                const float* __restrict__ bias,
                                                float* __restrict__ c) {
    const int wid  = (blockIdx.x * 256 + threadIdx.x) >> 6;   // global wave id = (n,o)
    const int lane = threadIdx.x & 63;
    const int n = wid >> 11;        // / OUT
    const int o = wid & (OUT - 1);

    const float4* wp = reinterpret_cast<const float4*>(W + (size_t)(n * OUT + o) * D + lane * 8);
    const float4* vp = reinterpret_cast<const float4*>(V + (size_t)n * D + lane * 8);
    float4 w0 = wp[0], w1 = wp[1];
    float4 v0 = vp[0], v1 = vp[1];
    float s = w0.x * v0.x + w0.y * v0.y + w0.z * v0.z + w0.w * v0.w
            + w1.x * v1.x + w1.y * v1.y + w1.z * v1.z + w1.w * v1.w;
    #pragma unroll
    for (int off = 32; off > 0; off >>= 1) s += __shfl_down(s, off);
    if (lane == 0) c[n * OUT + o] = bias[n * OUT + o] - s;
}

// ---------------- Kernel 2: fused GEMM + relu + n-sum ----------------
__global__ __launch_bounds__(256) void main_kernel(const float* __restrict__ S,
                                                   const float* __restrict__ W,
                                                   const float* __restrict__ C,
                                                   float* __restrict__ out) {
    // A-tile: 128 rows x 512 k of bf16, XOR-swizzled in 16B chunks (T2-style):
    // chunk (row, kc) stored at kc ^ (row & 7)  -> stride-1024B frag reads become 2-way (free).
    __shared__ unsigned short As[BM * D];   // 128 KiB

    const int t    = threadIdx.x;
    const int lane = t & 63;
    const int w    = t >> 6;                  // wave 0..3, owns 16 o-cols
    const int ob0  = blockIdx.x * BO;
    const int bm0  = blockIdx.y * BM;
    const int l15  = lane & 15;
    const int lg   = lane >> 4;               // 16-lane group 0..3

    // ---- stage A = S[bm0:bm0+BM, :] as bf16 (once per block) ----
    #pragma unroll
    for (int i = 0; i < (BM * D / 8) / 256; ++i) {   // 32 chunks of 8 elems per thread
        int cid = i * 256 + t;
        int row = cid >> 6;            // 64 chunks per row
        int kc  = cid & 63;
        const float4* sp = reinterpret_cast<const float4*>(S + (size_t)(bm0 + row) * D + kc * 8);
        bf16x8 val = cvt8(sp[0], sp[1]);
        *reinterpret_cast<bf16x8*>(&As[row * D + ((kc ^ (row & 7)) * 8)]) = val;
    }
    __syncthreads();

    const int ocol = ob0 + w * 16 + l15;      // this lane's o-column (B-frag col = lane&15)

    f32x4 oacc[8];
    #pragma unroll
    for (int mi = 0; mi < 8; ++mi) oacc[mi] = (f32x4){0.f, 0.f, 0.f, 0.f};

    for (int n = 0; n < N; ++n) {
        const float cv = C[n * OUT + ocol];   // c for this lane's column (all rows share it)

        f32x4 pre[8];
        #pragma unroll
        for (int mi = 0; mi < 8; ++mi) pre[mi] = (f32x4){0.f, 0.f, 0.f, 0.f};

        // W row for this lane: W[n][ocol][k], lane provides k = ks*32 + lg*8 + 0..7
        const float* wrow = W + (size_t)(n * OUT + ocol) * D + lg * 8;

        #pragma unroll
        for (int ks = 0; ks < 16; ++ks) {
            float4 wa = *reinterpret_cast<const float4*>(wrow + ks * 32);
            float4 wb = *reinterpret_cast<const float4*>(wrow + ks * 32 + 4);
            bf16x8 bq = cvt8(wa, wb);

            const int kc = ks * 4 + lg;       // 16B chunk index along k
            #pragma unroll
            for (int mi = 0; mi < 8; ++mi) {
                const int row = mi * 16 + l15;
                bf16x8 aq = *reinterpret_cast<const bf16x8*>(
                    &As[row * D + ((kc ^ (row & 7)) * 8)]);
                pre[mi] = __builtin_amdgcn_mfma_f32_16x16x32_bf16(aq, bq, pre[mi], 0, 0, 0);
            }
        }

        #pragma unroll
        for (int mi = 0; mi < 8; ++mi)
            #pragma unroll
            for (int r = 0; r < 4; ++r)
                oacc[mi][r] += fmaxf(pre[mi][r] + cv, 0.f);
    }

    // ---- store: C/D layout col = lane&15, row = (lane>>4)*4 + r (m89-verified) ----
    #pragma unroll
    for (int mi = 0; mi < 8; ++mi) {
        #pragma unroll
        for (int r = 0; r < 4; ++r) {
            int row = bm0 + mi * 16 + lg * 4 + r;
            out[(size_t)row * OUT + ocol] = oacc[mi][r];
        }
    }
}

extern "C" void kernel_launch(void* const* d_in, const int* in_sizes, int n_in,
                              void* d_out, int out_size, void* d_ws, size_t ws_size,
                              hipStream_t stream) {
    const float* S    = (const float*)d_in[0];   // semantic_vec [B, D]
    const float* V    = (const float*)d_in[1];   // vertices     [N, D]
    const float* W    = (const float*)d_in[2];   // W            [N, OUT, D]
    const float* bias = (const float*)d_in[3];   // b            [N, OUT]
    float* out = (float*)d_out;                  // [B, OUT] f32
    float* c   = (float*)d_ws;                   // [N, OUT] f32 scratch (512 KiB)

    // Kernel 1: one wave per (n,o); 4 waves per block.
    c_kernel<<<dim3((N * OUT) / 4), dim3(256), 0, stream>>>(V, W, bias, c);

    // Kernel 2: 32 x 8 = 256 blocks (1 per CU), 256 threads.
    main_kernel<<<dim3(OUT / BO, B / BM), dim3(256), 0, stream>>>(S, W, c, out);
}

// Round 2
// 303.090 us; speedup vs baseline: 3.1513x; 3.1513x over previous
//
#include <hip/hip_runtime.h>
#include <hip/hip_bf16.h>

// out[b,o] = sum_n relu( (s[b]-v[n]) . W[n,o,:] + bias[n,o] )
//          = sum_n relu( s[b].W[n,o,:] + c[n,o] ),  c[n,o] = bias[n,o] - v[n].W[n,o,:]
//
// Single fused kernel:
//  - A = S staged once per block in swizzled LDS (bf16).
//  - W fragments global->reg, converted fp32->bf16 in flight; the same fragment
//    also FMAs into a per-lane v.W accumulator (c computed on the fly, fp32).
//  - NB=4 branches processed per K-step: each A-frag ds_read feeds 4 MFMAs.
//  - 8 waves: 4 o-groups x 2 n-halves; cross-half reduction through LDS at the end.

typedef __attribute__((ext_vector_type(8))) short  bf16x8;
typedef __attribute__((ext_vector_type(4))) float  f32x4;

constexpr int B   = 1024;
constexpr int N   = 64;
constexpr int D   = 512;
constexpr int OUT = 2048;

constexpr int BM  = 128;   // rows (b) per block
constexpr int BO  = 64;    // cols (o) per block; 4 waves x 16 cols
constexpr int TPB = 512;   // 8 waves

static __device__ __forceinline__ unsigned short f2bf(float f) {
    unsigned int u = __builtin_bit_cast(unsigned int, f);
    u += 0x7FFFu + ((u >> 16) & 1u);
    return (unsigned short)(u >> 16);
}

static __device__ __forceinline__ bf16x8 cvt8(float4 a, float4 b) {
    bf16x8 r;
    r[0] = (short)f2bf(a.x); r[1] = (short)f2bf(a.y);
    r[2] = (short)f2bf(a.z); r[3] = (short)f2bf(a.w);
    r[4] = (short)f2bf(b.x); r[5] = (short)f2bf(b.y);
    r[6] = (short)f2bf(b.z); r[7] = (short)f2bf(b.w);
    return r;
}

__global__ __launch_bounds__(TPB) void main_kernel(const float* __restrict__ S,
                                                   const float* __restrict__ W,
                                                   const float* __restrict__ V,
                                                   const float* __restrict__ bias,
                                                   float* __restrict__ out) {
    // A-tile: 128 rows x 512 k bf16, XOR-swizzled in 16B chunks: kc ^ (row&7).
    __shared__ unsigned short As[BM * D];   // 128 KiB

    const int t    = threadIdx.x;
    const int lane = t & 63;
    const int w    = t >> 6;          // 0..7
    const int og   = w & 3;           // o-group (16 cols)
    const int ng   = w >> 2;          // n-half: 0 -> n<32, 1 -> n>=32
    const int l15  = lane & 15;
    const int lg   = lane >> 4;       // 0..3
    const int ob0  = blockIdx.x * BO;
    const int bm0  = blockIdx.y * BM;
    const int ocol = ob0 + og * 16 + l15;

    // ---- stage A = S[bm0:bm0+BM, :] as bf16 (once per block) ----
    #pragma unroll
    for (int i = 0; i < (BM * D / 8) / TPB; ++i) {   // 16 iters
        int cid = i * TPB + t;
        int row = cid >> 6;            // 64 chunks per row
        int kc  = cid & 63;
        const float4* sp = reinterpret_cast<const float4*>(S + (size_t)(bm0 + row) * D + kc * 8);
        bf16x8 val = cvt8(sp[0], sp[1]);
        *reinterpret_cast<bf16x8*>(&As[row * D + ((kc ^ (row & 7)) * 8)]) = val;
    }
    __syncthreads();

    f32x4 oacc[8];
    #pragma unroll
    for (int mi = 0; mi < 8; ++mi) oacc[mi] = (f32x4){0.f, 0.f, 0.f, 0.f};

    const int kofs = lg * 8;   // this lane's base k offset within a 32-k step

    for (int nc = 0; nc < 8; ++nc) {
        const int n0 = ng * 32 + nc * 4;

        f32x4 pre[4][8];
        #pragma unroll
        for (int j = 0; j < 4; ++j)
            #pragma unroll
            for (int mi = 0; mi < 8; ++mi) pre[j][mi] = (f32x4){0.f, 0.f, 0.f, 0.f};

        float cacc[4] = {0.f, 0.f, 0.f, 0.f};

        const float* wbase = W + ((size_t)n0 * OUT + ocol) * D + kofs;
        const float* vbase = V + (size_t)n0 * D + kofs;

        #pragma unroll 2
        for (int ks = 0; ks < 16; ++ks) {
            bf16x8 bq[4];
            #pragma unroll
            for (int j = 0; j < 4; ++j) {
                const float* wr = wbase + (size_t)j * (OUT * D) + ks * 32;
                float4 wa = *reinterpret_cast<const float4*>(wr);
                float4 wb = *reinterpret_cast<const float4*>(wr + 4);
                const float* vr = vbase + (size_t)j * D + ks * 32;
                float4 va = *reinterpret_cast<const float4*>(vr);
                float4 vb = *reinterpret_cast<const float4*>(vr + 4);
                cacc[j] += wa.x * va.x + wa.y * va.y + wa.z * va.z + wa.w * va.w
                         + wb.x * vb.x + wb.y * vb.y + wb.z * vb.z + wb.w * vb.w;
                bq[j] = cvt8(wa, wb);
            }
            const int kc = ks * 4 + lg;
            #pragma unroll
            for (int mi = 0; mi < 8; ++mi) {
                const int row = mi * 16 + l15;
                bf16x8 aq = *reinterpret_cast<const bf16x8*>(
                    &As[row * D + ((kc ^ (row & 7)) * 8)]);
                pre[0][mi] = __builtin_amdgcn_mfma_f32_16x16x32_bf16(aq, bq[0], pre[0][mi], 0, 0, 0);
                pre[1][mi] = __builtin_amdgcn_mfma_f32_16x16x32_bf16(aq, bq[1], pre[1][mi], 0, 0, 0);
                pre[2][mi] = __builtin_amdgcn_mfma_f32_16x16x32_bf16(aq, bq[2], pre[2][mi], 0, 0, 0);
                pre[3][mi] = __builtin_amdgcn_mfma_f32_16x16x32_bf16(aq, bq[3], pre[3][mi], 0, 0, 0);
            }
        }

        // c[n,ocol] = bias - dot(v, W[n,ocol,:]): reduce the 4 lg partials.
        #pragma unroll
        for (int j = 0; j < 4; ++j) {
            float cs = cacc[j];
            cs += __shfl_xor(cs, 16);
            cs += __shfl_xor(cs, 32);
            const float cv = bias[(n0 + j) * OUT + ocol] - cs;
            #pragma unroll
            for (int mi = 0; mi < 8; ++mi)
                #pragma unroll
                for (int r = 0; r < 4; ++r)
                    oacc[mi][r] += fmaxf(pre[j][mi][r] + cv, 0.f);
        }
    }

    // ---- cross n-half reduction through LDS, then store ----
    __syncthreads();                      // everyone done reading As
    float* red = reinterpret_cast<float*>(As);
    if (ng == 1) {
        #pragma unroll
        for (int mi = 0; mi < 8; ++mi)
            *reinterpret_cast<f32x4*>(&red[(og * 64 + lane) * 32 + mi * 4]) = oacc[mi];
    }
    __syncthreads();
    if (ng == 0) {
        #pragma unroll
        for (int mi = 0; mi < 8; ++mi) {
            f32x4 o2 = *reinterpret_cast<const f32x4*>(&red[(og * 64 + lane) * 32 + mi * 4]);
            #pragma unroll
            for (int r = 0; r < 4; ++r) {
                int row = bm0 + mi * 16 + lg * 4 + r;
                out[(size_t)row * OUT + ocol] = oacc[mi][r] + o2[r];
            }
        }
    }
}

extern "C" void kernel_launch(void* const* d_in, const int* in_sizes, int n_in,
                              void* d_out, int out_size, void* d_ws, size_t ws_size,
                              hipStream_t stream) {
    const float* S    = (const float*)d_in[0];   // semantic_vec [B, D]
    const float* V    = (const float*)d_in[1];   // vertices     [N, D]
    const float* W    = (const float*)d_in[2];   // W            [N, OUT, D]
    const float* bias = (const float*)d_in[3];   // b            [N, OUT]
    float* out = (float*)d_out;                  // [B, OUT] f32

    main_kernel<<<dim3(OUT / BO, B / BM), dim3(TPB), 0, stream>>>(S, W, V, bias, out);
}

// Round 3
// 199.316 us; speedup vs baseline: 4.7920x; 1.5207x over previous
//
#include <hip/hip_runtime.h>
#include <hip/hip_bf16.h>

// out[b,o] = sum_n relu( (s[b]-v[n]) . W[n,o,:] + bias[n,o] )
//          = sum_n relu( s[b].W[n,o,:] + c[n,o] ),  c[n,o] = bias[n,o] - v[n].W[n,o,:]
//
// Kernel P (prep, memory-bound): Wbf16 = cvt(W) into d_ws, and c[n,o] into d_ws
//   (computed from the fp32 W already in registers -> no extra traffic).
// Kernel M (main, MFMA-bound): A = S staged once per block in swizzled LDS;
//   W fragments are single bf16x8 global loads (no cvt, no dot in the hot loop).
//   NB=4 branches per K-step so each A-frag ds_read feeds 4 MFMAs.
//   8 waves: 4 o-groups x 2 n-halves; cross-half reduction through LDS at the end.
// Fallback (ws too small): round-2 fused kernel.

typedef __attribute__((ext_vector_type(8))) short  bf16x8;
typedef __attribute__((ext_vector_type(4))) short  bf16x4;
typedef __attribute__((ext_vector_type(4))) float  f32x4;

constexpr int B   = 1024;
constexpr int N   = 64;
constexpr int D   = 512;
constexpr int OUT = 2048;

constexpr int BM  = 128;   // rows (b) per block
constexpr int BO  = 64;    // cols (o) per block; 4 waves x 16 cols
constexpr int TPB = 512;   // 8 waves

static __device__ __forceinline__ unsigned short f2bf(float f) {
    unsigned int u = __builtin_bit_cast(unsigned int, f);
    u += 0x7FFFu + ((u >> 16) & 1u);
    return (unsigned short)(u >> 16);
}

static __device__ __forceinline__ bf16x4 cvt4(float4 a) {
    bf16x4 r;
    r[0] = (short)f2bf(a.x); r[1] = (short)f2bf(a.y);
    r[2] = (short)f2bf(a.z); r[3] = (short)f2bf(a.w);
    return r;
}

static __device__ __forceinline__ bf16x8 cvt8(float4 a, float4 b) {
    bf16x8 r;
    r[0] = (short)f2bf(a.x); r[1] = (short)f2bf(a.y);
    r[2] = (short)f2bf(a.z); r[3] = (short)f2bf(a.w);
    r[4] = (short)f2bf(b.x); r[5] = (short)f2bf(b.y);
    r[6] = (short)f2bf(b.z); r[7] = (short)f2bf(b.w);
    return r;
}

// ---------------- Kernel P: Wb = bf16(W); c = bias - v.W ----------------
__global__ __launch_bounds__(256) void prep_kernel(const float* __restrict__ W,
                                                   const float* __restrict__ V,
                                                   const float* __restrict__ bias,
                                                   unsigned short* __restrict__ Wb,
                                                   float* __restrict__ c) {
    const int wid  = (blockIdx.x * 256 + threadIdx.x) >> 6;   // row id = n*OUT + o
    const int lane = threadIdx.x & 63;
    const int n = wid >> 11;          // / OUT

    const size_t rbase = (size_t)wid * D;
    // two coalesced half-rows: k = lane*4 .. +4  and  k = 256 + lane*4 .. +4
    float4 w0 = *reinterpret_cast<const float4*>(W + rbase + lane * 4);
    float4 w1 = *reinterpret_cast<const float4*>(W + rbase + 256 + lane * 4);
    float4 v0 = *reinterpret_cast<const float4*>(V + (size_t)n * D + lane * 4);
    float4 v1 = *reinterpret_cast<const float4*>(V + (size_t)n * D + 256 + lane * 4);

    *reinterpret_cast<bf16x4*>(Wb + rbase + lane * 4)       = cvt4(w0);
    *reinterpret_cast<bf16x4*>(Wb + rbase + 256 + lane * 4) = cvt4(w1);

    float s = w0.x * v0.x + w0.y * v0.y + w0.z * v0.z + w0.w * v0.w
            + w1.x * v1.x + w1.y * v1.y + w1.z * v1.z + w1.w * v1.w;
    #pragma unroll
    for (int off = 1; off < 64; off <<= 1) s += __shfl_xor(s, off);
    if (lane == 0) c[wid] = bias[wid] - s;
}

// ---------------- Kernel M: fused GEMM + relu + n-sum (bf16 W from ws) ----------------
__global__ __launch_bounds__(TPB) void main_kernel(const float* __restrict__ S,
                                                   const unsigned short* __restrict__ Wb,
                                                   const float* __restrict__ C,
                                                   float* __restrict__ out) {
    // A-tile: 128 rows x 512 k bf16, XOR-swizzled in 16B chunks: kc ^ (row&7).
    __shared__ unsigned short As[BM * D];   // 128 KiB

    const int t    = threadIdx.x;
    const int lane = t & 63;
    const int w    = t >> 6;          // 0..7
    const int og   = w & 3;           // o-group (16 cols)
    const int ng   = w >> 2;          // n-half: 0 -> n<32, 1 -> n>=32
    const int l15  = lane & 15;
    const int lg   = lane >> 4;       // 0..3
    const int ob0  = blockIdx.x * BO;
    const int bm0  = blockIdx.y * BM;
    const int ocol = ob0 + og * 16 + l15;

    // ---- stage A = S[bm0:bm0+BM, :] as bf16 (once per block) ----
    #pragma unroll
    for (int i = 0; i < (BM * D / 8) / TPB; ++i) {   // 16 iters
        int cid = i * TPB + t;
        int row = cid >> 6;            // 64 chunks per row
        int kc  = cid & 63;
        const float4* sp = reinterpret_cast<const float4*>(S + (size_t)(bm0 + row) * D + kc * 8);
        bf16x8 val = cvt8(sp[0], sp[1]);
        *reinterpret_cast<bf16x8*>(&As[row * D + ((kc ^ (row & 7)) * 8)]) = val;
    }
    __syncthreads();

    f32x4 oacc[8];
    #pragma unroll
    for (int mi = 0; mi < 8; ++mi) oacc[mi] = (f32x4){0.f, 0.f, 0.f, 0.f};

    const int kofs = lg * 8;   // this lane's base k offset within a 32-k step

    for (int nc = 0; nc < 8; ++nc) {
        const int n0 = ng * 32 + nc * 4;

        f32x4 pre[4][8];
        #pragma unroll
        for (int j = 0; j < 4; ++j)
            #pragma unroll
            for (int mi = 0; mi < 8; ++mi) pre[j][mi] = (f32x4){0.f, 0.f, 0.f, 0.f};

        const unsigned short* wbase = Wb + ((size_t)n0 * OUT + ocol) * D + kofs;

        #pragma unroll 2
        for (int ks = 0; ks < 16; ++ks) {
            bf16x8 bq[4];
            #pragma unroll
            for (int j = 0; j < 4; ++j)
                bq[j] = *reinterpret_cast<const bf16x8*>(wbase + (size_t)j * (OUT * D) + ks * 32);

            const int kc = ks * 4 + lg;
            #pragma unroll
            for (int mi = 0; mi < 8; ++mi) {
                const int row = mi * 16 + l15;
                bf16x8 aq = *reinterpret_cast<const bf16x8*>(
                    &As[row * D + ((kc ^ (row & 7)) * 8)]);
                pre[0][mi] = __builtin_amdgcn_mfma_f32_16x16x32_bf16(aq, bq[0], pre[0][mi], 0, 0, 0);
                pre[1][mi] = __builtin_amdgcn_mfma_f32_16x16x32_bf16(aq, bq[1], pre[1][mi], 0, 0, 0);
                pre[2][mi] = __builtin_amdgcn_mfma_f32_16x16x32_bf16(aq, bq[2], pre[2][mi], 0, 0, 0);
                pre[3][mi] = __builtin_amdgcn_mfma_f32_16x16x32_bf16(aq, bq[3], pre[3][mi], 0, 0, 0);
            }
        }

        #pragma unroll
        for (int j = 0; j < 4; ++j) {
            const float cv = C[(n0 + j) * OUT + ocol];
            #pragma unroll
            for (int mi = 0; mi < 8; ++mi)
                #pragma unroll
                for (int r = 0; r < 4; ++r)
                    oacc[mi][r] += fmaxf(pre[j][mi][r] + cv, 0.f);
        }
    }

    // ---- cross n-half reduction through LDS, then store ----
    __syncthreads();                      // everyone done reading As
    float* red = reinterpret_cast<float*>(As);
    if (ng == 1) {
        #pragma unroll
        for (int mi = 0; mi < 8; ++mi)
            *reinterpret_cast<f32x4*>(&red[(og * 64 + lane) * 32 + mi * 4]) = oacc[mi];
    }
    __syncthreads();
    if (ng == 0) {
        #pragma unroll
        for (int mi = 0; mi < 8; ++mi) {
            f32x4 o2 = *reinterpret_cast<const f32x4*>(&red[(og * 64 + lane) * 32 + mi * 4]);
            #pragma unroll
            for (int r = 0; r < 4; ++r) {
                int row = bm0 + mi * 16 + lg * 4 + r;
                out[(size_t)row * OUT + ocol] = oacc[mi][r] + o2[r];
            }
        }
    }
}

// ---------------- Fallback (round-2 fused fp32-W kernel), used if ws too small ----------------
__global__ __launch_bounds__(TPB) void fused_kernel(const float* __restrict__ S,
                                                    const float* __restrict__ W,
                                                    const float* __restrict__ V,
                                                    const float* __restrict__ bias,
                                                    float* __restrict__ out) {
    __shared__ unsigned short As[BM * D];

    const int t    = threadIdx.x;
    const int lane = t & 63;
    const int w    = t >> 6;
    const int og   = w & 3;
    const int ng   = w >> 2;
    const int l15  = lane & 15;
    const int lg   = lane >> 4;
    const int ob0  = blockIdx.x * BO;
    const int bm0  = blockIdx.y * BM;
    const int ocol = ob0 + og * 16 + l15;

    #pragma unroll
    for (int i = 0; i < (BM * D / 8) / TPB; ++i) {
        int cid = i * TPB + t;
        int row = cid >> 6;
        int kc  = cid & 63;
        const float4* sp = reinterpret_cast<const float4*>(S + (size_t)(bm0 + row) * D + kc * 8);
        bf16x8 val = cvt8(sp[0], sp[1]);
        *reinterpret_cast<bf16x8*>(&As[row * D + ((kc ^ (row & 7)) * 8)]) = val;
    }
    __syncthreads();

    f32x4 oacc[8];
    #pragma unroll
    for (int mi = 0; mi < 8; ++mi) oacc[mi] = (f32x4){0.f, 0.f, 0.f, 0.f};

    const int kofs = lg * 8;

    for (int nc = 0; nc < 8; ++nc) {
        const int n0 = ng * 32 + nc * 4;

        f32x4 pre[4][8];
        #pragma unroll
        for (int j = 0; j < 4; ++j)
            #pragma unroll
            for (int mi = 0; mi < 8; ++mi) pre[j][mi] = (f32x4){0.f, 0.f, 0.f, 0.f};

        float cacc[4] = {0.f, 0.f, 0.f, 0.f};

        const float* wbase = W + ((size_t)n0 * OUT + ocol) * D + kofs;
        const float* vbase = V + (size_t)n0 * D + kofs;

        #pragma unroll 2
        for (int ks = 0; ks < 16; ++ks) {
            bf16x8 bq[4];
            #pragma unroll
            for (int j = 0; j < 4; ++j) {
                const float* wr = wbase + (size_t)j * (OUT * D) + ks * 32;
                float4 wa = *reinterpret_cast<const float4*>(wr);
                float4 wb = *reinterpret_cast<const float4*>(wr + 4);
                const float* vr = vbase + (size_t)j * D + ks * 32;
                float4 va = *reinterpret_cast<const float4*>(vr);
                float4 vb = *reinterpret_cast<const float4*>(vr + 4);
                cacc[j] += wa.x * va.x + wa.y * va.y + wa.z * va.z + wa.w * va.w
                         + wb.x * vb.x + wb.y * vb.y + wb.z * vb.z + wb.w * vb.w;
                bq[j] = cvt8(wa, wb);
            }
            const int kc = ks * 4 + lg;
            #pragma unroll
            for (int mi = 0; mi < 8; ++mi) {
                const int row = mi * 16 + l15;
                bf16x8 aq = *reinterpret_cast<const bf16x8*>(
                    &As[row * D + ((kc ^ (row & 7)) * 8)]);
                pre[0][mi] = __builtin_amdgcn_mfma_f32_16x16x32_bf16(aq, bq[0], pre[0][mi], 0, 0, 0);
                pre[1][mi] = __builtin_amdgcn_mfma_f32_16x16x32_bf16(aq, bq[1], pre[1][mi], 0, 0, 0);
                pre[2][mi] = __builtin_amdgcn_mfma_f32_16x16x32_bf16(aq, bq[2], pre[2][mi], 0, 0, 0);
                pre[3][mi] = __builtin_amdgcn_mfma_f32_16x16x32_bf16(aq, bq[3], pre[3][mi], 0, 0, 0);
            }
        }

        #pragma unroll
        for (int j = 0; j < 4; ++j) {
            float cs = cacc[j];
            cs += __shfl_xor(cs, 16);
            cs += __shfl_xor(cs, 32);
            const float cv = bias[(n0 + j) * OUT + ocol] - cs;
            #pragma unroll
            for (int mi = 0; mi < 8; ++mi)
                #pragma unroll
                for (int r = 0; r < 4; ++r)
                    oacc[mi][r] += fmaxf(pre[j][mi][r] + cv, 0.f);
        }
    }

    __syncthreads();
    float* red = reinterpret_cast<float*>(As);
    if (ng == 1) {
        #pragma unroll
        for (int mi = 0; mi < 8; ++mi)
            *reinterpret_cast<f32x4*>(&red[(og * 64 + lane) * 32 + mi * 4]) = oacc[mi];
    }
    __syncthreads();
    if (ng == 0) {
        #pragma unroll
        for (int mi = 0; mi < 8; ++mi) {
            f32x4 o2 = *reinterpret_cast<const f32x4*>(&red[(og * 64 + lane) * 32 + mi * 4]);
            #pragma unroll
            for (int r = 0; r < 4; ++r) {
                int row = bm0 + mi * 16 + lg * 4 + r;
                out[(size_t)row * OUT + ocol] = oacc[mi][r] + o2[r];
            }
        }
    }
}

extern "C" void kernel_launch(void* const* d_in, const int* in_sizes, int n_in,
                              void* d_out, int out_size, void* d_ws, size_t ws_size,
                              hipStream_t stream) {
    const float* S    = (const float*)d_in[0];   // semantic_vec [B, D]
    const float* V    = (const float*)d_in[1];   // vertices     [N, D]
    const float* W    = (const float*)d_in[2];   // W            [N, OUT, D]
    const float* bias = (const float*)d_in[3];   // b            [N, OUT]
    float* out = (float*)d_out;                  // [B, OUT] f32

    const size_t wb_bytes = (size_t)N * OUT * D * sizeof(unsigned short); // 128 MiB
    const size_t c_bytes  = (size_t)N * OUT * sizeof(float);              // 512 KiB

    if (ws_size >= wb_bytes + c_bytes) {
        unsigned short* Wb = (unsigned short*)d_ws;
        float* c = (float*)((char*)d_ws + wb_bytes);
        prep_kernel<<<dim3((N * OUT) / 4), dim3(256), 0, stream>>>(W, V, bias, Wb, c);
        main_kernel<<<dim3(OUT / BO, B / BM), dim3(TPB), 0, stream>>>(S, Wb, c, out);
    } else {
        fused_kernel<<<dim3(OUT / BO, B / BM), dim3(TPB), 0, stream>>>(S, W, V, bias, out);
    }
}